// Round 10
// baseline (62.462 us; speedup 1.0000x reference)
//
#include <hip/hip_runtime.h>
#include <math.h>

#define T_STEPS 256
#define BATCH   128
#define DIMD    512
#define NROWS   (T_STEPS * BATCH)   // 32768
#define PF      16                  // scan rolling-prefetch depth
#define GEMV_BLOCKS 2048            // 16 rows/block, 4 rows/wave
#define WRITER_BLOCKS 129           // 2 timesteps per 512-thread block

#define INV2PI  0.15915494309189535f
#define L2E     1.4426950408889634f
#define TWO_L2E 2.8853900817779268f

#define AGENT __HIP_MEMORY_SCOPE_AGENT

typedef float f32x4 __attribute__((ext_vector_type(4)));

#if __has_builtin(__builtin_amdgcn_sinf)
#define HW_SIN(x) __builtin_amdgcn_sinf(x)   // sin(2*pi*x), x in revolutions
#else
__device__ __forceinline__ float HW_SIN(float x) { return __sinf(x * 6.283185307179586f); }
#endif
#if __has_builtin(__builtin_amdgcn_exp2f)
#define EXP2(x) __builtin_amdgcn_exp2f(x)
#else
#define EXP2(x) exp2f(x)
#endif
#if __has_builtin(__builtin_amdgcn_rcpf)
#define RCP(x) __builtin_amdgcn_rcpf(x)
#else
#define RCP(x) (1.0f / (x))
#endif

// Quad broadcast via DPP quad_perm (full-rate VALU, no LDS pipe).
#if __has_builtin(__builtin_amdgcn_mov_dpp)
template <int CTRL>
__device__ __forceinline__ float quad_bcast(float x) {
    int xi = __builtin_bit_cast(int, x);
    int r  = __builtin_amdgcn_mov_dpp(xi, CTRL, 0xF, 0xF, true);
    return __builtin_bit_cast(float, r);
}
#else
template <int CTRL>
__device__ __forceinline__ float quad_bcast(float x) {
    const int src = (threadIdx.x & ~3) + (CTRL & 3);   // CTRL=0x00/0x55/0xAA/0xFF
    return __shfl(x, src & 63);
}
#endif

// Agent-scope relaxed ops (sc-flagged; no wbl2/inv cache maintenance).
__device__ __forceinline__ void  st_rlx(float* p, float v) {
    __hip_atomic_store(p, v, __ATOMIC_RELAXED, AGENT);
}
__device__ __forceinline__ void  st_rlx_i(int* p, int v) {
    __hip_atomic_store(p, v, __ATOMIC_RELAXED, AGENT);
}
__device__ __forceinline__ int   ld_rlx_i(const int* p) {
    return __hip_atomic_load(p, __ATOMIC_RELAXED, AGENT);
}
#define CFENCE()  asm volatile("" ::: "memory")

// ---------------------------------------------------------------------------
// prep: block 0 = qconsts (4 gates, one wave each); blocks 1.. = gemv
// (4 rows/wave). Pure producers; dispatch boundary publishes gc and X.
// gc[4g+0]=scale*A, gc[4g+1]=scale*R, gc[4g+2]=phi_rev, gc[4g+3]=sumWh/2pi
// scale = -L2E (sigmoid f,i,o) or +2*L2E (tanh g).
// X[(t*B+b)*4+g] = (dot_g + b0_g)/2pi  (phase added in the scan at refill).
// ---------------------------------------------------------------------------
__global__ __launch_bounds__(256) void prep(
    const float* __restrict__ inp,
    const float* __restrict__ Wf, const float* __restrict__ Wi,
    const float* __restrict__ Wg, const float* __restrict__ Wo,
    const float* __restrict__ bfp, const float* __restrict__ bip,
    const float* __restrict__ bgp, const float* __restrict__ bop,
    const float* __restrict__ Pf, const float* __restrict__ Pi,
    const float* __restrict__ Pg, const float* __restrict__ Po,
    float* __restrict__ gc, int* __restrict__ hProg,
    float4* __restrict__ X4)
{
    const int bid  = blockIdx.x;
    const int wv   = threadIdx.x >> 6;
    const int lane = threadIdx.x & 63;

    if (bid == 0) {
        // ================= qconsts =================
        if (threadIdx.x == 0) { hProg[0] = 0; hProg[1] = 0; }
        const int g = wv;
        const float* P = (g == 0) ? Pf : (g == 1) ? Pi : (g == 2) ? Pg : Po;
        const float* W = (g == 0) ? Wf : (g == 1) ? Wi : (g == 2) ? Wg : Wo;

        __shared__ float s0r[4][256], s0i[4][256], s1r[4][256], s1i[4][256];

#pragma unroll
        for (int j = 0; j < 4; ++j) {
            const int k = lane + 64 * j;
            s0r[g][k] = (k == 0)   ? 1.0f : 0.0f;  s0i[g][k] = 0.0f;
            s1r[g][k] = (k == 128) ? 1.0f : 0.0f;  s1i[g][k] = 0.0f;
        }
        __syncthreads();

        for (int l = 0; l < 2; ++l) {
            for (int w = 0; w < 8; ++w) {
                const float phi = P[l * 24 + w * 3 + 0];
                const float th  = P[l * 24 + w * 3 + 1];
                const float om  = P[l * 24 + w * 3 + 2];
                float sh, chh; __sincosf(0.5f * th, &sh, &chh);
                float sp, cp;  __sincosf(0.5f * (phi + om), &sp, &cp);
                float sm, cm;  __sincosf(0.5f * (phi - om), &sm, &cm);
                const float m00r =  cp * chh, m00i = -sp * chh;
                const float m01r = -cm * sh,  m01i = -sm * sh;
                const float m10r =  cm * sh,  m10i = -sm * sh;
                const float m11r =  cp * chh, m11i =  sp * chh;

                const int shift = 7 - w;
                const int mask  = 1 << shift;

                float n0r[4], n0i[4], n1r[4], n1i[4];
#pragma unroll
                for (int j = 0; j < 4; ++j) {
                    const int k  = lane + 64 * j;
                    const int bit = (k >> shift) & 1;
                    const int i0 = k & ~mask, i1 = k | mask;
                    const float a0r = s0r[g][i0], a0i = s0i[g][i0];
                    const float a1r = s0r[g][i1], a1i = s0i[g][i1];
                    const float b0r = s1r[g][i0], b0i = s1i[g][i0];
                    const float b1r = s1r[g][i1], b1i = s1i[g][i1];
                    const float mr0 = bit ? m10r : m00r, mi0 = bit ? m10i : m00i;
                    const float mr1 = bit ? m11r : m01r, mi1 = bit ? m11i : m01i;
                    n0r[j] = mr0 * a0r - mi0 * a0i + mr1 * a1r - mi1 * a1i;
                    n0i[j] = mr0 * a0i + mi0 * a0r + mr1 * a1i + mi1 * a1r;
                    n1r[j] = mr0 * b0r - mi0 * b0i + mr1 * b1r - mi1 * b1i;
                    n1i[j] = mr0 * b0i + mi0 * b0r + mr1 * b1i + mi1 * b1r;
                }
                __syncthreads();
#pragma unroll
                for (int j = 0; j < 4; ++j) {
                    const int k = lane + 64 * j;
                    s0r[g][k] = n0r[j]; s0i[g][k] = n0i[j];
                    s1r[g][k] = n1r[j]; s1i[g][k] = n1i[j];
                }
                __syncthreads();
            }
            // CNOT chain permutation
            float n0r[4], n0i[4], n1r[4], n1i[4];
#pragma unroll
            for (int j = 0; j < 4; ++j) {
                int src = lane + 64 * j;
                for (int w = 6; w >= 0; --w) {
                    const int cb = (src >> (7 - w)) & 1;
                    src ^= cb << (6 - w);
                }
                n0r[j] = s0r[g][src]; n0i[j] = s0i[g][src];
                n1r[j] = s1r[g][src]; n1i[j] = s1i[g][src];
            }
            __syncthreads();
#pragma unroll
            for (int j = 0; j < 4; ++j) {
                const int k = lane + 64 * j;
                s0r[g][k] = n0r[j]; s0i[g][k] = n0i[j];
                s1r[g][k] = n1r[j]; s1i[g][k] = n1i[j];
            }
            __syncthreads();
        }

        float t00 = 0, t11 = 0, t01 = 0;
#pragma unroll
        for (int j = 0; j < 4; ++j) {
            const int k = lane + 64 * j;
            const float z = (k < 128) ? 1.0f : -1.0f;
            t00 += z * (s0r[g][k] * s0r[g][k] + s0i[g][k] * s0i[g][k]);
            t11 += z * (s1r[g][k] * s1r[g][k] + s1i[g][k] * s1i[g][k]);
            t01 += z * (s0i[g][k] * s1r[g][k] - s0r[g][k] * s1i[g][k]);
        }
        float tsw = 0;
#pragma unroll
        for (int j = 0; j < 8; ++j) tsw += W[512 + lane + 64 * j];

        for (int off = 32; off; off >>= 1) {
            t00 += __shfl_xor(t00, off);
            t11 += __shfl_xor(t11, off);
            t01 += __shfl_xor(t01, off);
            tsw += __shfl_xor(tsw, off);
        }
        if (lane == 0) {
            const float A  = 0.5f * (t00 + t11);
            const float Bc = 0.5f * (t00 - t11);
            const float Bs = -t01;
            const float R  = sqrtf(Bc * Bc + Bs * Bs);
            const float ph = atan2f(Bc, Bs) * INV2PI;
            const float sc = (g == 2) ? TWO_L2E : -L2E;
            gc[4 * g + 0] = sc * A;
            gc[4 * g + 1] = sc * R;
            gc[4 * g + 2] = ph;
            gc[4 * g + 3] = tsw * INV2PI;
        }
        return;
    }

    // ================= gemv: 4 rows per wave =================
    const int rowbase = (bid - 1) * 16 + wv * 4;

    const float4* wfp = (const float4*)Wf;
    const float4* wip = (const float4*)Wi;
    const float4* wgp = (const float4*)Wg;
    const float4* wop = (const float4*)Wo;
    const float4 fa = wfp[lane], fb = wfp[lane + 64];
    const float4 ia = wip[lane], ib = wip[lane + 64];
    const float4 ga = wgp[lane], gb = wgp[lane + 64];
    const float4 oa = wop[lane], ob = wop[lane + 64];

    const float4* xr = (const float4*)(inp + (size_t)rowbase * DIMD);
    float sums[4][4];   // [row][gate]
#pragma unroll
    for (int r = 0; r < 4; ++r) {
        const float4 xa = xr[r * 128 + lane];
        const float4 xb = xr[r * 128 + lane + 64];
        sums[r][0] = xa.x * fa.x + xa.y * fa.y + xa.z * fa.z + xa.w * fa.w
                   + xb.x * fb.x + xb.y * fb.y + xb.z * fb.z + xb.w * fb.w;
        sums[r][1] = xa.x * ia.x + xa.y * ia.y + xa.z * ia.z + xa.w * ia.w
                   + xb.x * ib.x + xb.y * ib.y + xb.z * ib.z + xb.w * ib.w;
        sums[r][2] = xa.x * ga.x + xa.y * ga.y + xa.z * ga.z + xa.w * ga.w
                   + xb.x * gb.x + xb.y * gb.y + xb.z * gb.z + xb.w * gb.w;
        sums[r][3] = xa.x * oa.x + xa.y * oa.y + xa.z * oa.z + xa.w * oa.w
                   + xb.x * ob.x + xb.y * ob.y + xb.z * ob.z + xb.w * ob.w;
    }
#pragma unroll
    for (int r = 0; r < 4; ++r)
#pragma unroll
        for (int g = 0; g < 4; ++g)
            for (int off = 32; off; off >>= 1)
                sums[r][g] += __shfl_xor(sums[r][g], off);

    if (lane == 0) {
        const float b0f = bfp[0], b0i = bip[0], b0g = bgp[0], b0o = bop[0];
#pragma unroll
        for (int r = 0; r < 4; ++r) {
            X4[rowbase + r] = make_float4((sums[r][0] + b0f) * INV2PI,
                                          (sums[r][1] + b0i) * INV2PI,
                                          (sums[r][2] + b0g) * INV2PI,
                                          (sums[r][3] + b0o) * INV2PI);
        }
    }
}

// ---------------------------------------------------------------------------
// Fused scan + broadcast. Grid 130 x 512.
// Block 0: lane-parallel scan — quad of lanes per chain (lane&3 = gate),
// 128 chains = 512 threads = 8 waves. Per step/lane: sin+exp2 for own gate,
// DPP quad-broadcast of e's, redundant c/h update. Publishes hProg every
// 32 steps via __syncthreads (vm drain) + single counter.
// Blocks 1..129: writers, 2 timesteps per block (wv>>2), quarter = wv&3;
// deficit-proportional sleep, NT output stores.
// ---------------------------------------------------------------------------
__global__ __launch_bounds__(512) void scan_write(
    const float* __restrict__ Xs, const float* __restrict__ gc,
    float* __restrict__ Hs, float* __restrict__ cfin,
    float4* __restrict__ out4, int* __restrict__ hProg)
{
    const int bid  = blockIdx.x;
    const int tid  = threadIdx.x;
    const int wv   = tid >> 6;
    const int lane = tid & 63;

    if (bid == 0) {
        // ---------------- scan ----------------
        const int g  = tid & 3;        // gate
        const int cb = tid >> 2;       // chain 0..127
        const float A  = gc[4 * g + 0];
        const float R  = gc[4 * g + 1];
        const float ph = gc[4 * g + 2];
        const float sw = gc[4 * g + 3];

        float p[PF];
#pragma unroll
        for (int j = 0; j < PF; ++j) p[j] = Xs[j * 512 + tid] + ph;

        float c = 0.0f, h = 0.0f;
        for (int tb = 0; tb < T_STEPS; tb += PF) {
#pragma unroll
            for (int j = 0; j < PF; ++j) {
                const int t = tb + j;
                const float xv = p[j];
                p[j] = Xs[(t + PF) * 512 + tid] + ph;  // branchless refill (pad)

                const float th = fmaf(h, sw, xv);
                const float e  = EXP2(fmaf(R, HW_SIN(th), A));
                const float vf = quad_bcast<0x00>(e);
                const float vi = quad_bcast<0x55>(e);
                const float vg = quad_bcast<0xAA>(e);
                const float vo = quad_bcast<0xFF>(e);
                const float Ff = vf + 1.0f, Fi = vi + 1.0f;
                const float Fg = vg + 1.0f, Fo = vo + 1.0f;
                const float FiFg = Fi * Fg;
                const float num  = fmaf(c, FiFg, (vg - 1.0f) * Ff);
                c = num * RCP(Ff * FiFg);
                const float ec = EXP2(c * TWO_L2E);
                h = (ec - 1.0f) * RCP(Fo * (ec + 1.0f));
                if (g == 0) st_rlx(&Hs[t * BATCH + cb], h);
            }
            if (tb == T_STEPS - PF && g == 0) st_rlx(&cfin[cb], c);
            if (((tb + PF) & 31) == 0) {        // publish every 32 steps
                __syncthreads();                 // drains vmem + barrier
                if (tid == 0) st_rlx_i(&hProg[0], tb + PF);
            }
        }
        return;
    }

    // ---------------- writers ----------------
    const int t  = 2 * (bid - 1) + (wv >> 2);   // 0..257 (256=hx, 257=cx)
    const int qd = wv & 3;                      // quarter: b in [qd*32,+32)
    const int need = (t < 256) ? (t + 1) : 256;

    int cur = ld_rlx_i(&hProg[0]);
    while (cur < need) {
        int loops = ((need - cur) >> 5) + 1;    // ~1 sleep-pair per 32 steps
        for (int s = 0; s < loops; ++s) {
            __builtin_amdgcn_s_sleep(32);
            __builtin_amdgcn_s_sleep(32);
        }
        cur = ld_rlx_i(&hProg[0]);
    }
    CFENCE();

    const float* src = (t == 257) ? cfin : (Hs + ((t >= 256 ? 255 : t) * BATCH));
    const float hv = src[qd * 32 + (lane & 31)];

    size_t base = (t < 256) ? ((size_t)t * 16384)
                : (t == 256 ? (size_t)4194304 : (size_t)4210688);
    base += (size_t)qd * 4096;
#pragma unroll 8
    for (int j = 0; j < 64; ++j) {
        const float v = __shfl(hv, j >> 1);
        const f32x4 val = {v, v, v, v};
        __builtin_nontemporal_store(val, (f32x4*)(out4 + base + j * 64 + lane));
    }
}

extern "C" void kernel_launch(void* const* d_in, const int* in_sizes, int n_in,
                              void* d_out, int out_size, void* d_ws, size_t ws_size,
                              hipStream_t stream)
{
    const float* inp = (const float*)d_in[0];
    const float* Wf  = (const float*)d_in[1];
    const float* bfv = (const float*)d_in[2];
    const float* Pf  = (const float*)d_in[3];
    const float* Wi  = (const float*)d_in[4];
    const float* biv = (const float*)d_in[5];
    const float* Pi  = (const float*)d_in[6];
    const float* Wg  = (const float*)d_in[7];
    const float* bgv = (const float*)d_in[8];
    const float* Pg  = (const float*)d_in[9];
    const float* Wo  = (const float*)d_in[10];
    const float* bov = (const float*)d_in[11];
    const float* Po  = (const float*)d_in[12];

    float4* X4   = (float4*)d_ws;                     // NROWS + PF*BATCH
    float*  Hs   = (float*)(X4 + NROWS + PF * BATCH); // 32768
    float*  cfin = Hs + NROWS;                        // 128
    float*  gc   = cfin + BATCH;                      // 16
    int*    hProg = (int*)(gc + 16);                  // 2

    prep<<<1 + GEMV_BLOCKS, 256, 0, stream>>>(inp, Wf, Wi, Wg, Wo,
                                              bfv, biv, bgv, bov,
                                              Pf, Pi, Pg, Po,
                                              gc, hProg, X4);
    scan_write<<<1 + WRITER_BLOCKS, 512, 0, stream>>>((const float*)X4, gc,
                                                      Hs, cfin,
                                                      (float4*)d_out, hProg);
}

// Round 11
// 55.188 us; speedup vs baseline: 1.1318x; 1.1318x over previous
//
#include <hip/hip_runtime.h>
#include <math.h>

#define T_STEPS 256
#define BATCH   128
#define DIMD    512
#define NROWS   (T_STEPS * BATCH)   // 32768
#define PF      16                  // chunk size / prefetch depth
#define WRITER_BLOCKS 258
#define GEMV_BLOCKS 2048            // 16 rows/block, 4 rows/wave

#define INV2PI  0.15915494309189535f
#define L2E     1.4426950408889634f
#define TWO_L2E 2.8853900817779268f

#define AGENT __HIP_MEMORY_SCOPE_AGENT

typedef float f32x4 __attribute__((ext_vector_type(4)));

#if __has_builtin(__builtin_amdgcn_sinf)
#define HW_SIN(x) __builtin_amdgcn_sinf(x)   // sin(2*pi*x), x in revolutions
#else
__device__ __forceinline__ float HW_SIN(float x) { return __sinf(x * 6.283185307179586f); }
#endif
#if __has_builtin(__builtin_amdgcn_exp2f)
#define EXP2(x) __builtin_amdgcn_exp2f(x)
#else
#define EXP2(x) exp2f(x)
#endif
#if __has_builtin(__builtin_amdgcn_rcpf)
#define RCP(x) __builtin_amdgcn_rcpf(x)
#else
#define RCP(x) (1.0f / (x))
#endif

// Agent-scope relaxed ops (sc-flagged; no wbl2/inv cache maintenance).
__device__ __forceinline__ void  st_rlx(float* p, float v) {
    __hip_atomic_store(p, v, __ATOMIC_RELAXED, AGENT);
}
__device__ __forceinline__ void  st_rlx_i(int* p, int v) {
    __hip_atomic_store(p, v, __ATOMIC_RELAXED, AGENT);
}
__device__ __forceinline__ int   ld_rlx_i(const int* p) {
    return __hip_atomic_load(p, __ATOMIC_RELAXED, AGENT);
}
#define VMFENCE() asm volatile("s_waitcnt vmcnt(0)" ::: "memory")
#define CFENCE()  asm volatile("" ::: "memory")

// ---------------------------------------------------------------------------
// prep: block 0 = qconsts (4 gates, one wave each); blocks 1.. = gemv
// (4 rows/wave). Pure producers; dispatch boundary publishes gc and X4.
// gc[4g+0]=scale*A, gc[4g+1]=scale*R, gc[4g+2]=phi_rev, gc[4g+3]=sumWh/2pi
// scale = -L2E (sigmoid f,i,o) or +2*L2E (tanh g).
// X4[t*B+b] = (dot + b0)/2pi  (phase added in the scan at chunk copy).
// ---------------------------------------------------------------------------
__global__ __launch_bounds__(256) void prep(
    const float* __restrict__ inp,
    const float* __restrict__ Wf, const float* __restrict__ Wi,
    const float* __restrict__ Wg, const float* __restrict__ Wo,
    const float* __restrict__ bfp, const float* __restrict__ bip,
    const float* __restrict__ bgp, const float* __restrict__ bop,
    const float* __restrict__ Pf, const float* __restrict__ Pi,
    const float* __restrict__ Pg, const float* __restrict__ Po,
    float* __restrict__ gc, int* __restrict__ hProg,
    float4* __restrict__ X4)
{
    const int bid  = blockIdx.x;
    const int wv   = threadIdx.x >> 6;
    const int lane = threadIdx.x & 63;

    if (bid == 0) {
        // ================= qconsts =================
        if (threadIdx.x == 0) { hProg[0] = 0; hProg[1] = 0; }
        const int g = wv;
        const float* P = (g == 0) ? Pf : (g == 1) ? Pi : (g == 2) ? Pg : Po;
        const float* W = (g == 0) ? Wf : (g == 1) ? Wi : (g == 2) ? Wg : Wo;

        __shared__ float s0r[4][256], s0i[4][256], s1r[4][256], s1i[4][256];

#pragma unroll
        for (int j = 0; j < 4; ++j) {
            const int k = lane + 64 * j;
            s0r[g][k] = (k == 0)   ? 1.0f : 0.0f;  s0i[g][k] = 0.0f;
            s1r[g][k] = (k == 128) ? 1.0f : 0.0f;  s1i[g][k] = 0.0f;
        }
        __syncthreads();

        for (int l = 0; l < 2; ++l) {
            for (int w = 0; w < 8; ++w) {
                const float phi = P[l * 24 + w * 3 + 0];
                const float th  = P[l * 24 + w * 3 + 1];
                const float om  = P[l * 24 + w * 3 + 2];
                float sh, chh; __sincosf(0.5f * th, &sh, &chh);
                float sp, cp;  __sincosf(0.5f * (phi + om), &sp, &cp);
                float sm, cm;  __sincosf(0.5f * (phi - om), &sm, &cm);
                const float m00r =  cp * chh, m00i = -sp * chh;
                const float m01r = -cm * sh,  m01i = -sm * sh;
                const float m10r =  cm * sh,  m10i = -sm * sh;
                const float m11r =  cp * chh, m11i =  sp * chh;

                const int shift = 7 - w;
                const int mask  = 1 << shift;

                float n0r[4], n0i[4], n1r[4], n1i[4];
#pragma unroll
                for (int j = 0; j < 4; ++j) {
                    const int k  = lane + 64 * j;
                    const int bit = (k >> shift) & 1;
                    const int i0 = k & ~mask, i1 = k | mask;
                    const float a0r = s0r[g][i0], a0i = s0i[g][i0];
                    const float a1r = s0r[g][i1], a1i = s0i[g][i1];
                    const float b0r = s1r[g][i0], b0i = s1i[g][i0];
                    const float b1r = s1r[g][i1], b1i = s1i[g][i1];
                    const float mr0 = bit ? m10r : m00r, mi0 = bit ? m10i : m00i;
                    const float mr1 = bit ? m11r : m01r, mi1 = bit ? m11i : m01i;
                    n0r[j] = mr0 * a0r - mi0 * a0i + mr1 * a1r - mi1 * a1i;
                    n0i[j] = mr0 * a0i + mi0 * a0r + mr1 * a1i + mi1 * a1r;
                    n1r[j] = mr0 * b0r - mi0 * b0i + mr1 * b1r - mi1 * b1i;
                    n1i[j] = mr0 * b0i + mi0 * b0r + mr1 * b1i + mi1 * b1r;
                }
                __syncthreads();
#pragma unroll
                for (int j = 0; j < 4; ++j) {
                    const int k = lane + 64 * j;
                    s0r[g][k] = n0r[j]; s0i[g][k] = n0i[j];
                    s1r[g][k] = n1r[j]; s1i[g][k] = n1i[j];
                }
                __syncthreads();
            }
            // CNOT chain permutation
            float n0r[4], n0i[4], n1r[4], n1i[4];
#pragma unroll
            for (int j = 0; j < 4; ++j) {
                int src = lane + 64 * j;
                for (int w = 6; w >= 0; --w) {
                    const int cb = (src >> (7 - w)) & 1;
                    src ^= cb << (6 - w);
                }
                n0r[j] = s0r[g][src]; n0i[j] = s0i[g][src];
                n1r[j] = s1r[g][src]; n1i[j] = s1i[g][src];
            }
            __syncthreads();
#pragma unroll
            for (int j = 0; j < 4; ++j) {
                const int k = lane + 64 * j;
                s0r[g][k] = n0r[j]; s0i[g][k] = n0i[j];
                s1r[g][k] = n1r[j]; s1i[g][k] = n1i[j];
            }
            __syncthreads();
        }

        float t00 = 0, t11 = 0, t01 = 0;
#pragma unroll
        for (int j = 0; j < 4; ++j) {
            const int k = lane + 64 * j;
            const float z = (k < 128) ? 1.0f : -1.0f;
            t00 += z * (s0r[g][k] * s0r[g][k] + s0i[g][k] * s0i[g][k]);
            t11 += z * (s1r[g][k] * s1r[g][k] + s1i[g][k] * s1i[g][k]);
            t01 += z * (s0i[g][k] * s1r[g][k] - s0r[g][k] * s1i[g][k]);
        }
        float tsw = 0;
#pragma unroll
        for (int j = 0; j < 8; ++j) tsw += W[512 + lane + 64 * j];

        for (int off = 32; off; off >>= 1) {
            t00 += __shfl_xor(t00, off);
            t11 += __shfl_xor(t11, off);
            t01 += __shfl_xor(t01, off);
            tsw += __shfl_xor(tsw, off);
        }
        if (lane == 0) {
            const float A  = 0.5f * (t00 + t11);
            const float Bc = 0.5f * (t00 - t11);
            const float Bs = -t01;
            const float R  = sqrtf(Bc * Bc + Bs * Bs);
            const float ph = atan2f(Bc, Bs) * INV2PI;
            const float sc = (g == 2) ? TWO_L2E : -L2E;
            gc[4 * g + 0] = sc * A;
            gc[4 * g + 1] = sc * R;
            gc[4 * g + 2] = ph;
            gc[4 * g + 3] = tsw * INV2PI;
        }
        return;
    }

    // ================= gemv: 4 rows per wave =================
    const int rowbase = (bid - 1) * 16 + wv * 4;

    const float4* wfp = (const float4*)Wf;
    const float4* wip = (const float4*)Wi;
    const float4* wgp = (const float4*)Wg;
    const float4* wop = (const float4*)Wo;
    const float4 fa = wfp[lane], fb = wfp[lane + 64];
    const float4 ia = wip[lane], ib = wip[lane + 64];
    const float4 ga = wgp[lane], gb = wgp[lane + 64];
    const float4 oa = wop[lane], ob = wop[lane + 64];

    const float4* xr = (const float4*)(inp + (size_t)rowbase * DIMD);
    float sums[4][4];   // [row][gate]
#pragma unroll
    for (int r = 0; r < 4; ++r) {
        const float4 xa = xr[r * 128 + lane];
        const float4 xb = xr[r * 128 + lane + 64];
        sums[r][0] = xa.x * fa.x + xa.y * fa.y + xa.z * fa.z + xa.w * fa.w
                   + xb.x * fb.x + xb.y * fb.y + xb.z * fb.z + xb.w * fb.w;
        sums[r][1] = xa.x * ia.x + xa.y * ia.y + xa.z * ia.z + xa.w * ia.w
                   + xb.x * ib.x + xb.y * ib.y + xb.z * ib.z + xb.w * ib.w;
        sums[r][2] = xa.x * ga.x + xa.y * ga.y + xa.z * ga.z + xa.w * ga.w
                   + xb.x * gb.x + xb.y * gb.y + xb.z * gb.z + xb.w * gb.w;
        sums[r][3] = xa.x * oa.x + xa.y * oa.y + xa.z * oa.z + xa.w * oa.w
                   + xb.x * ob.x + xb.y * ob.y + xb.z * ob.z + xb.w * ob.w;
    }
#pragma unroll
    for (int r = 0; r < 4; ++r)
#pragma unroll
        for (int g = 0; g < 4; ++g)
            for (int off = 32; off; off >>= 1)
                sums[r][g] += __shfl_xor(sums[r][g], off);

    if (lane == 0) {
        const float b0f = bfp[0], b0i = bip[0], b0g = bgp[0], b0o = bop[0];
#pragma unroll
        for (int r = 0; r < 4; ++r) {
            X4[rowbase + r] = make_float4((sums[r][0] + b0f) * INV2PI,
                                          (sums[r][1] + b0i) * INV2PI,
                                          (sums[r][2] + b0g) * INV2PI,
                                          (sums[r][3] + b0o) * INV2PI);
        }
    }
}

// ---------------------------------------------------------------------------
// Fused scan + broadcast. Grid 259 x 256.
// Block 0 (waves 0,1): recurrence, 64 chains/wave. CHUNKED double-buffer
// prefetch (q loaded at chunk start, p consumed — zero in-loop vmem waits).
// Publishes hProg[wv] only at t=64/128/192/256 (drains are cheap there:
// outstanding q-batch is >=16 steps old).
// Blocks 1..258: writers (deficit-proportional sleep, NT output stores).
// ---------------------------------------------------------------------------
__global__ __launch_bounds__(256) void scan_write(
    const float4* __restrict__ X4, const float* __restrict__ gc,
    float* __restrict__ Hs, float* __restrict__ cfin,
    float4* __restrict__ out4, int* __restrict__ hProg)
{
    const int bid  = blockIdx.x;
    const int wv   = threadIdx.x >> 6;
    const int lane = threadIdx.x & 63;

    if (bid == 0) {
        // ---------------- scan ----------------
        if (threadIdx.x >= BATCH) return;
        const int b = threadIdx.x;

        const float Af = gc[0],  Rf = gc[1],  phf = gc[2],  swf = gc[3];
        const float Ai = gc[4],  Ri = gc[5],  phi_ = gc[6], swi = gc[7];
        const float Ag = gc[8],  Rg = gc[9],  phg = gc[10], swg = gc[11];
        const float Ao = gc[12], Ro = gc[13], pho = gc[14], swo = gc[15];

        float4 p[PF], q[PF];
#pragma unroll
        for (int j = 0; j < PF; ++j) {
            const float4 v = X4[j * BATCH + b];
            p[j] = make_float4(v.x + phf, v.y + phi_, v.z + phg, v.w + pho);
        }

        float c = 0.0f, h = 0.0f;
        for (int k = 0; k < T_STEPS / PF; ++k) {
            const int tb = k * PF;
            // issue next chunk's loads up front (pad covers k=15)
#pragma unroll
            for (int j = 0; j < PF; ++j) q[j] = X4[(tb + PF + j) * BATCH + b];
#pragma unroll
            for (int j = 0; j < PF; ++j) {
                const float4 xv = p[j];
                const float thf = fmaf(h, swf, xv.x);
                const float thi = fmaf(h, swi, xv.y);
                const float thg = fmaf(h, swg, xv.z);
                const float tho = fmaf(h, swo, xv.w);
                // e = exp(-E_raw) for f,i,o ; exp(+2 E_raw) for g
                const float ef = EXP2(fmaf(Rf, HW_SIN(thf), Af));
                const float ei = EXP2(fmaf(Ri, HW_SIN(thi), Ai));
                const float eg = EXP2(fmaf(Rg, HW_SIN(thg), Ag));
                const float eo = EXP2(fmaf(Ro, HW_SIN(tho), Ao));
                const float Ff = ef + 1.0f, Fi = ei + 1.0f;
                const float Fg = eg + 1.0f, Fo = eo + 1.0f;
                const float FiFg = Fi * Fg;
                const float num  = fmaf(c, FiFg, (eg - 1.0f) * Ff);
                c = num * RCP(Ff * FiFg);                    // c' (single rcp)
                const float ec = EXP2(c * TWO_L2E);
                h = (ec - 1.0f) * RCP(Fo * (ec + 1.0f));     // o*tanh(c)
                st_rlx(&Hs[(tb + j) * BATCH + b], h);
            }
            if (k == T_STEPS / PF - 1) st_rlx(&cfin[b], c);
            if ((k & 3) == 3) {            // publish at t = 64,128,192,256
                VMFENCE();
                if (lane == 0) st_rlx_i(&hProg[wv], tb + PF);
            }
#pragma unroll
            for (int j = 0; j < PF; ++j) {
                p[j] = make_float4(q[j].x + phf, q[j].y + phi_,
                                   q[j].z + phg, q[j].w + pho);
            }
        }
        return;
    }

    // ---------------- writers ----------------
    const int t  = bid - 1;           // 0..257 (256=hx, 257=cx)
    const int qd = wv;                // quarter: b in [qd*32, qd*32+32)
    const int pidx = (qd < 2) ? 0 : 1;
    const int need = (t < 256) ? ((t >> 6) + 1) << 6 : 256;

    int cur = ld_rlx_i(&hProg[pidx]);
    while (cur < need) {
        int loops = ((need - cur) >> 5) + 1;   // ~1 sleep-pair per 32 steps
        for (int s = 0; s < loops; ++s) {
            __builtin_amdgcn_s_sleep(32);
            __builtin_amdgcn_s_sleep(32);
        }
        cur = ld_rlx_i(&hProg[pidx]);
    }
    CFENCE();

    const float* src = (t == 257) ? cfin : (Hs + ((t >= 256 ? 255 : t) * BATCH));
    const float hv = src[qd * 32 + (lane & 31)];

    size_t base = (t < 256) ? ((size_t)t * 16384)
                : (t == 256 ? (size_t)4194304 : (size_t)4210688);
    base += (size_t)qd * 4096;
#pragma unroll 8
    for (int j = 0; j < 64; ++j) {
        const float v = __shfl(hv, j >> 1);
        const f32x4 val = {v, v, v, v};
        __builtin_nontemporal_store(val, (f32x4*)(out4 + base + j * 64 + lane));
    }
}

extern "C" void kernel_launch(void* const* d_in, const int* in_sizes, int n_in,
                              void* d_out, int out_size, void* d_ws, size_t ws_size,
                              hipStream_t stream)
{
    const float* inp = (const float*)d_in[0];
    const float* Wf  = (const float*)d_in[1];
    const float* bfv = (const float*)d_in[2];
    const float* Pf  = (const float*)d_in[3];
    const float* Wi  = (const float*)d_in[4];
    const float* biv = (const float*)d_in[5];
    const float* Pi  = (const float*)d_in[6];
    const float* Wg  = (const float*)d_in[7];
    const float* bgv = (const float*)d_in[8];
    const float* Pg  = (const float*)d_in[9];
    const float* Wo  = (const float*)d_in[10];
    const float* bov = (const float*)d_in[11];
    const float* Po  = (const float*)d_in[12];

    float4* X4   = (float4*)d_ws;                     // NROWS + PF*BATCH
    float*  Hs   = (float*)(X4 + NROWS + PF * BATCH); // 32768
    float*  cfin = Hs + NROWS;                        // 128
    float*  gc   = cfin + BATCH;                      // 16
    int*    hProg = (int*)(gc + 16);                  // 2

    prep<<<1 + GEMV_BLOCKS, 256, 0, stream>>>(inp, Wf, Wi, Wg, Wo,
                                              bfv, biv, bgv, bov,
                                              Pf, Pi, Pg, Po,
                                              gc, hProg, X4);
    scan_write<<<1 + WRITER_BLOCKS, 256, 0, stream>>>(X4, gc, Hs, cfin,
                                                      (float4*)d_out, hProg);
}